// Round 6
// baseline (511.710 us; speedup 1.0000x reference)
//
#include <hip/hip_runtime.h>
#include <math.h>

// Problem constants (setup_inputs): B=8, C=256, H=64, W=256
#define BH_ 64
#define BW_ 256
constexpr size_t HW = (size_t)BH_ * BW_;   // 16384

using f32x4  = __attribute__((ext_vector_type(4))) float;
using short8 = __attribute__((ext_vector_type(8))) short;

__device__ __forceinline__ short f2bf(float f) {
    unsigned u = __float_as_uint(f);
    u += 0x7fffu + ((u >> 16) & 1u);     // RNE to bf16
    return (short)(u >> 16);
}

// XCD-aware block swizzle: consecutive logical ids land on the same XCD.
// gridDim.x is always kc*256 (divisible by 8) -> bijective.
__device__ __forceinline__ int xcd_swizzle() {
    const int rb  = blockIdx.x;
    const int cpx = gridDim.x >> 3;
    return (rb & 7) * cpx + (rb >> 3);
}

// ---------------------------------------------------------------------------
// Prep: pw1/pw2 -> bf16 (same (CO,CI) layout, k-contiguous for MFMA B);
//       pw3 -> fp32 transposed (CI,CO) for the fp32 layer-3 kernel.
// ---------------------------------------------------------------------------
__global__ __launch_bounds__(256)
void prep_kernel(const float* __restrict__ p1,   // (128,256)
                 const float* __restrict__ p2,   // (64,128)
                 const float* __restrict__ p3,   // (32,64)
                 short* __restrict__ wb1,        // (128,256) bf16
                 short* __restrict__ wb2,        // (64,128) bf16
                 float* __restrict__ wt3)        // (64,32) f32
{
    int idx = blockIdx.x * 256 + threadIdx.x;
    if (idx < 128 * 256) {
        wb1[idx] = f2bf(p1[idx]);
    } else if (idx < 128 * 256 + 64 * 128) {
        int r = idx - 128 * 256;
        wb2[r] = f2bf(p2[r]);
    } else if (idx < 128 * 256 + 64 * 128 + 32 * 64) {
        int r = idx - (128 * 256 + 64 * 128);
        int ci = r / 32, co = r % 32;
        wt3[r] = p3[co * 64 + ci];
    }
}

// ---------------------------------------------------------------------------
// MFMA depthwise-separable layer (bf16 GEMM, fp32 dw): layers 1 and 2.
// Single-buffer (15 KB LDS), 8 blocks/CU via __launch_bounds__(256,8):
// latency hiding via TLP. Tile: 64 px of one row x CO. K chunks of 32.
// A=[px][ci] bf16 pad-40, B=[co][ci] pad-40, XOR-swizzled.
// mfma_f32_16x16x32_bf16: A m=lane&15,k=(lane>>4)*8+e; B n=lane&15 same k;
// D col(n)=lane&15, row(m)=(lane>>4)*4+r.
// ---------------------------------------------------------------------------
template<int CI, int CO>
__global__ __launch_bounds__(256, 8)
void dsconv_mfma(const float* __restrict__ xin,   // (kc, CI, H, W)
                 const float* __restrict__ dww,   // (CI, 9)
                 const float* __restrict__ dwb,   // (CI)
                 const short* __restrict__ wBf,   // (CO, CI) bf16
                 const float* __restrict__ pwb,   // (CO)
                 float* __restrict__ out)         // (kc, CO, H, W)
{
    constexpr int CIC = 32;
    constexpr int PX  = 64;
    constexpr int NT  = CO / 16;
    constexpr int WNT = NT / 4;            // n-tiles per wave (2 L1, 1 L2)
    constexpr int ST  = 40;                // padded row stride in shorts
    constexpr int SPT = (CO * CIC) / 256;  // B shorts/thread
    constexpr int TPR = CIC / SPT;
    static_assert(NT % 4 == 0 && CI % CIC == 0, "geometry");

    __shared__ short Abuf[PX * ST];        // 5 KB
    __shared__ short Bbuf[CO * ST];        // 10 KB (L1) / 5 KB (L2)

    const int t    = threadIdx.x;
    const int w    = t >> 6;
    const int lane = t & 63;
    const int bid  = xcd_swizzle();
    const int jt   = bid & 3;              // W/64 = 4
    const int i    = (bid >> 2) & 63;      // H
    const int b    = bid >> 8;
    const int j0   = jt * PX;

    // dw mapping: one ci x 8 px per thread
    const int ci_l = t >> 3;               // 0..31
    const int g    = t & 7;
    const int jq   = j0 + g * 8;

    // mfma lane coords
    const int lm = lane & 15;
    const int kb = lane >> 4;

    f32x4 acc[4][WNT];
    #pragma unroll
    for (int q = 0; q < WNT; ++q) {
        float bv = pwb[(w * WNT + q) * 16 + lm];
        #pragma unroll
        for (int mt = 0; mt < 4; ++mt) {
            f32x4 z = {bv, bv, bv, bv};
            acc[mt][q] = z;
        }
    }

    for (int cc = 0; cc < CI; cc += CIC) {
        __syncthreads();   // previous chunk's MFMA reads done

        // ---- stage B chunk: (CO x 32) bf16, swizzled ----
        {
            const int co  = t / TPR;
            const int sub = t % TPR;
            const short* src = wBf + (size_t)co * CI + cc + sub * SPT;
            const int sbase = co * ST + sub * SPT;
            const int swz   = ((co >> 3) & 7) << 3;
            #pragma unroll
            for (int jj = 0; jj < SPT / 8; ++jj) {
                *reinterpret_cast<short8*>(&Bbuf[(sbase + jj * 8) ^ swz]) =
                    *reinterpret_cast<const short8*>(&src[jj * 8]);
            }
        }

        // ---- depthwise 3x3 chunk -> Abuf (bf16, swizzled) ----
        {
            const int ci = cc + ci_l;
            const float* wkp = dww + ci * 9;
            float wv[9];
            #pragma unroll
            for (int k = 0; k < 9; ++k) wv[k] = wkp[k];
            float o[8];
            float bv = dwb[ci];
            #pragma unroll
            for (int e = 0; e < 8; ++e) o[e] = bv;

            const float* xp = xin + ((size_t)b * CI + ci) * HW;
            #pragma unroll
            for (int di = -1; di <= 1; ++di) {
                int ii2 = i + di;
                if ((unsigned)ii2 < (unsigned)BH_) {
                    const float* xr = xp + (size_t)ii2 * BW_ + jq;
                    float v[10];
                    v[0] = (jq > 0) ? xr[-1] : 0.f;
                    float4 A = *reinterpret_cast<const float4*>(xr);
                    float4 Bq = *reinterpret_cast<const float4*>(xr + 4);
                    v[1] = A.x; v[2] = A.y; v[3] = A.z; v[4] = A.w;
                    v[5] = Bq.x; v[6] = Bq.y; v[7] = Bq.z; v[8] = Bq.w;
                    v[9] = (jq + 8 < BW_) ? xr[8] : 0.f;
                    const float w0 = wv[(di + 1) * 3 + 0];
                    const float w1 = wv[(di + 1) * 3 + 1];
                    const float w2 = wv[(di + 1) * 3 + 2];
                    #pragma unroll
                    for (int e = 0; e < 8; ++e)
                        o[e] += w0 * v[e] + w1 * v[e + 1] + w2 * v[e + 2];
                }
            }
            #pragma unroll
            for (int e = 0; e < 8; ++e) {
                int px = g * 8 + e;
                int sa = (px * ST + ci_l) ^ (((px >> 3) & 7) << 3);
                Abuf[sa] = f2bf(o[e]);
            }
        }

        __syncthreads();   // Abuf + Bbuf ready

        // ---- MFMA phase ----
        {
            short8 bfrag[WNT];
            #pragma unroll
            for (int q = 0; q < WNT; ++q) {
                int co = (w * WNT + q) * 16 + lm;
                int sa = (co * ST + kb * 8) ^ (((co >> 3) & 7) << 3);
                bfrag[q] = *reinterpret_cast<const short8*>(&Bbuf[sa]);
            }
            #pragma unroll
            for (int mt = 0; mt < 4; ++mt) {
                int px = mt * 16 + lm;
                int sa = (px * ST + kb * 8) ^ (((px >> 3) & 7) << 3);
                short8 af = *reinterpret_cast<const short8*>(&Abuf[sa]);
                #pragma unroll
                for (int q = 0; q < WNT; ++q)
                    acc[mt][q] = __builtin_amdgcn_mfma_f32_16x16x32_bf16(
                        af, bfrag[q], acc[mt][q], 0, 0, 0);
            }
        }
    }

    // ---- epilogue: ReLU + float4 stores (coalesced per co line) ----
    #pragma unroll
    for (int mt = 0; mt < 4; ++mt) {
        #pragma unroll
        for (int q = 0; q < WNT; ++q) {
            int co = (w * WNT + q) * 16 + lm;
            float* op = out + (((size_t)b * CO + co) * BH_ + i) * BW_
                        + j0 + mt * 16 + kb * 4;
            float4 v;
            v.x = fmaxf(acc[mt][q][0], 0.f);
            v.y = fmaxf(acc[mt][q][1], 0.f);
            v.z = fmaxf(acc[mt][q][2], 0.f);
            v.w = fmaxf(acc[mt][q][3], 0.f);
            *reinterpret_cast<float4*>(op) = v;
        }
    }
}

// ---------------------------------------------------------------------------
// fp32 depthwise-separable layer (layer 3 only).
// ---------------------------------------------------------------------------
template<int CI, int CO, int CPT>
__global__ __launch_bounds__(256, 8)
void dsconv_kernel(const float* __restrict__ xin,
                   const float* __restrict__ dww,
                   const float* __restrict__ dwb,
                   const float* __restrict__ wT,    // (CI, CO) transposed pw
                   const float* __restrict__ pwb,
                   float* __restrict__ out)
{
    constexpr int CIC = 32;
    constexpr int PX  = 64;
    static_assert(CO / CPT == 16, "co groups must be 16");

    __shared__ float dwbuf[CIC * PX];
    __shared__ float wbuf[CIC * CO];

    const int t   = threadIdx.x;
    const int bid = xcd_swizzle();
    const int jt  = bid & 3;
    const int i   = (bid >> 2) & 63;
    const int b   = bid >> 8;
    const int j0  = jt * PX;

    const int px_g = t & 15;
    const int co_g = t >> 4;
    const int co0  = co_g * CPT;
    const int p0   = px_g * 4;

    const int ci_local = t >> 3;
    const int g        = t & 7;
    const int jq       = j0 + g * 8;

    float acc[CPT][4];
    #pragma unroll
    for (int ii = 0; ii < CPT; ++ii) {
        float bv = pwb[co0 + ii];
        #pragma unroll
        for (int jj = 0; jj < 4; ++jj) acc[ii][jj] = bv;
    }

    for (int cc = 0; cc < CI; cc += CIC) {
        __syncthreads();
        {
            const float* src = wT + (size_t)cc * CO;
            #pragma unroll
            for (int idx = t * 4; idx < CIC * CO; idx += 1024)
                *reinterpret_cast<float4*>(&wbuf[idx]) =
                    *reinterpret_cast<const float4*>(&src[idx]);
        }
        {
            const int ci = cc + ci_local;
            const float* wk = dww + ci * 9;
            float w[9];
            #pragma unroll
            for (int k = 0; k < 9; ++k) w[k] = wk[k];
            float o[8];
            float bv = dwb[ci];
            #pragma unroll
            for (int e = 0; e < 8; ++e) o[e] = bv;

            const float* xp = xin + ((size_t)b * CI + ci) * HW;
            #pragma unroll
            for (int di = -1; di <= 1; ++di) {
                int ii2 = i + di;
                if ((unsigned)ii2 < (unsigned)BH_) {
                    const float* xr = xp + (size_t)ii2 * BW_ + jq;
                    float v[10];
                    v[0] = (jq > 0) ? xr[-1] : 0.f;
                    float4 A = *reinterpret_cast<const float4*>(xr);
                    float4 Bq = *reinterpret_cast<const float4*>(xr + 4);
                    v[1] = A.x; v[2] = A.y; v[3] = A.z; v[4] = A.w;
                    v[5] = Bq.x; v[6] = Bq.y; v[7] = Bq.z; v[8] = Bq.w;
                    v[9] = (jq + 8 < BW_) ? xr[8] : 0.f;
                    const float w0 = w[(di + 1) * 3 + 0];
                    const float w1 = w[(di + 1) * 3 + 1];
                    const float w2 = w[(di + 1) * 3 + 2];
                    #pragma unroll
                    for (int e = 0; e < 8; ++e)
                        o[e] += w0 * v[e] + w1 * v[e + 1] + w2 * v[e + 2];
                }
            }
            float4* dst = reinterpret_cast<float4*>(&dwbuf[ci_local * PX + g * 8]);
            dst[0] = make_float4(o[0], o[1], o[2], o[3]);
            dst[1] = make_float4(o[4], o[5], o[6], o[7]);
        }
        __syncthreads();

        #pragma unroll 4
        for (int k = 0; k < CIC; ++k) {
            float4 dq = *reinterpret_cast<const float4*>(&dwbuf[k * PX + p0]);
            float dv[4] = {dq.x, dq.y, dq.z, dq.w};
            float wv2[CPT];
            if constexpr (CPT == 2) {
                float2 wq = *reinterpret_cast<const float2*>(&wbuf[k * CO + co0]);
                wv2[0] = wq.x; wv2[1] = wq.y;
            } else {
                float4 wq = *reinterpret_cast<const float4*>(&wbuf[k * CO + co0]);
                #pragma unroll
                for (int ii = 0; ii < CPT && ii < 4; ++ii) wv2[ii] = (&wq.x)[ii];
            }
            #pragma unroll
            for (int ii = 0; ii < CPT; ++ii)
                #pragma unroll
                for (int jj = 0; jj < 4; ++jj)
                    acc[ii][jj] += wv2[ii] * dv[jj];
        }
    }

    #pragma unroll
    for (int ii = 0; ii < CPT; ++ii) {
        float4 v;
        v.x = fmaxf(acc[ii][0], 0.f);
        v.y = fmaxf(acc[ii][1], 0.f);
        v.z = fmaxf(acc[ii][2], 0.f);
        v.w = fmaxf(acc[ii][3], 0.f);
        float* op = out + (((size_t)b * CO + co0 + ii) * BH_ + i) * BW_ + j0 + p0;
        *reinterpret_cast<float4*>(op) = v;
    }
}

// ---------------------------------------------------------------------------
// Final fused kernel: dw4 + pw(32->9) + softmax + char_attn + dynamic conv.
// Dyn-conv: 4 px x 16 channels per thread (ar[9][4] = 36 VGPR) so the
// kernel fits the 64-VGPR / 8-waves-per-SIMD occupancy bin.
// ---------------------------------------------------------------------------
__global__ __launch_bounds__(256, 8)
void final_kernel(const float* __restrict__ x,
                  const float* __restrict__ a3,
                  const float* __restrict__ dww,
                  const float* __restrict__ dwb,
                  const float* __restrict__ pww,
                  const float* __restrict__ pwb,
                  float* __restrict__ out,
                  float* __restrict__ chat)
{
    constexpr int PX = 64;
    __shared__ float dwbuf[32 * PX];
    __shared__ float attL[9][PX];

    const int t   = threadIdx.x;
    const int bid = xcd_swizzle();
    const int jt  = bid & 3;
    const int i   = (bid >> 2) & 63;
    const int b   = bid >> 8;
    const int j0  = jt * PX;

    // ---- dw4 on a3: 32 ch x 64 px, sliding-window float4 ----
    {
        const int g  = t & 7;
        const int jq = j0 + g * 8;
        const int ci = t >> 3;
        const float* wk = dww + ci * 9;
        float w[9];
        #pragma unroll
        for (int k = 0; k < 9; ++k) w[k] = wk[k];
        float o[8];
        float bv = dwb[ci];
        #pragma unroll
        for (int e = 0; e < 8; ++e) o[e] = bv;

        const float* xp = a3 + ((size_t)b * 32 + ci) * HW;
        #pragma unroll
        for (int di = -1; di <= 1; ++di) {
            int ii2 = i + di;
            if ((unsigned)ii2 < (unsigned)BH_) {
                const float* xr = xp + (size_t)ii2 * BW_ + jq;
                float v[10];
                v[0] = (jq > 0) ? xr[-1] : 0.f;
                float4 A = *reinterpret_cast<const float4*>(xr);
                float4 Bq = *reinterpret_cast<const float4*>(xr + 4);
                v[1] = A.x; v[2] = A.y; v[3] = A.z; v[4] = A.w;
                v[5] = Bq.x; v[6] = Bq.y; v[7] = Bq.z; v[8] = Bq.w;
                v[9] = (jq + 8 < BW_) ? xr[8] : 0.f;
                const float w0 = w[(di + 1) * 3 + 0];
                const float w1 = w[(di + 1) * 3 + 1];
                const float w2 = w[(di + 1) * 3 + 2];
                #pragma unroll
                for (int e = 0; e < 8; ++e)
                    o[e] += w0 * v[e] + w1 * v[e + 1] + w2 * v[e + 2];
            }
        }
        float4* dst = reinterpret_cast<float4*>(&dwbuf[ci * PX + g * 8]);
        dst[0] = make_float4(o[0], o[1], o[2], o[3]);
        dst[1] = make_float4(o[4], o[5], o[6], o[7]);
    }
    __syncthreads();

    // ---- logits: 9 co x 64 px ----
    for (int idx = t; idx < 9 * PX; idx += 256) {
        int co = idx >> 6;
        int px = idx & 63;
        float acc = pwb[co];
        #pragma unroll
        for (int ci = 0; ci < 32; ++ci)
            acc += pww[co * 32 + ci] * dwbuf[ci * PX + px];
        attL[co][px] = acc;
    }
    __syncthreads();

    // ---- softmax over 9 taps ----
    if (t < PX) {
        float v[9];
        float m = -1e30f;
        #pragma unroll
        for (int k = 0; k < 9; ++k) { v[k] = attL[k][t]; m = fmaxf(m, v[k]); }
        float s = 0.f;
        #pragma unroll
        for (int k = 0; k < 9; ++k) { v[k] = __expf(v[k] - m); s += v[k]; }
        float inv = 1.f / s;
        #pragma unroll
        for (int k = 0; k < 9; ++k) attL[k][t] = v[k] * inv;
    }
    __syncthreads();

    // ---- char_attn: (b,i,j,9) contiguous ----
    {
        size_t base = (((size_t)b * BH_ + i) * BW_ + j0) * 9;
        for (int idx = t; idx < PX * 9; idx += 256)
            chat[base + idx] = attL[idx % 9][idx / 9];
    }

    // ---- att -> registers: 4 px per thread ----
    const int g4  = t & 15;
    const int c0  = t >> 4;
    const int jq4 = j0 + g4 * 4;
    float ar4[9][4];
    #pragma unroll
    for (int k = 0; k < 9; ++k) {
        float4 a0 = *reinterpret_cast<const float4*>(&attL[k][g4 * 4]);
        ar4[k][0] = a0.x; ar4[k][1] = a0.y; ar4[k][2] = a0.z; ar4[k][3] = a0.w;
    }

    // ---- dynamic 3x3 conv: 4 px x 16 channels per thread ----
    for (int c = c0; c < 256; c += 16) {
        const float* xp = x + ((size_t)b * 256 + c) * HW;
        float v3[3][6];
        #pragma unroll
        for (int di = 0; di < 3; ++di) {
            int ii2 = i + di - 1;
            if ((unsigned)ii2 < (unsigned)BH_) {
                const float* xr = xp + (size_t)ii2 * BW_ + jq4;
                v3[di][0] = (jq4 > 0) ? xr[-1] : 0.f;
                float4 A = *reinterpret_cast<const float4*>(xr);
                v3[di][1] = A.x; v3[di][2] = A.y; v3[di][3] = A.z; v3[di][4] = A.w;
                v3[di][5] = (jq4 + 4 < BW_) ? xr[4] : 0.f;
            } else {
                #pragma unroll
                for (int e = 0; e < 6; ++e) v3[di][e] = 0.f;
            }
        }
        float o[4] = {0.f, 0.f, 0.f, 0.f};
        #pragma unroll
        for (int di = 0; di < 3; ++di)
            #pragma unroll
            for (int dj = 0; dj < 3; ++dj)
                #pragma unroll
                for (int e = 0; e < 4; ++e)
                    o[e] += v3[di][e + dj] * ar4[di * 3 + dj][e];
        float* op = out + ((size_t)b * 256 + c) * HW + (size_t)i * BW_ + jq4;
        *reinterpret_cast<float4*>(op) = make_float4(o[0], o[1], o[2], o[3]);
    }
}

// ---------------------------------------------------------------------------
extern "C" void kernel_launch(void* const* d_in, const int* in_sizes, int n_in,
                              void* d_out, int out_size, void* d_ws, size_t ws_size,
                              hipStream_t stream)
{
    const float* x    = (const float*)d_in[0];
    const float* dw1w = (const float*)d_in[1];
    const float* dw1b = (const float*)d_in[2];
    const float* pw1w = (const float*)d_in[3];
    const float* pw1b = (const float*)d_in[4];
    const float* dw2w = (const float*)d_in[5];
    const float* dw2b = (const float*)d_in[6];
    const float* pw2w = (const float*)d_in[7];
    const float* pw2b = (const float*)d_in[8];
    const float* dw3w = (const float*)d_in[9];
    const float* dw3b = (const float*)d_in[10];
    const float* pw3w = (const float*)d_in[11];
    const float* pw3b = (const float*)d_in[12];
    const float* dw4w = (const float*)d_in[13];
    const float* dw4b = (const float*)d_in[14];
    const float* pw4w = (const float*)d_in[15];
    const float* pw4b = (const float*)d_in[16];

    float* outp = (float*)d_out;
    float* chat = outp + (size_t)8 * 256 * HW;

    // ws layout (bytes): wb1 bf16 65536 | wb2 bf16 16384 | wt3 f32 8192 | a1 | a2
    short* wb1 = (short*)d_ws;
    short* wb2 = wb1 + 128 * 256;
    float* wt3 = (float*)((char*)d_ws + 81920);
    float* abase = (float*)((char*)d_ws + 90112);

    int kmax = 1;
    for (int k = 8; k >= 1; k >>= 1) {
        size_t need = 90112 + (size_t)k * (128 + 64) * HW * sizeof(float);
        if (need <= ws_size) { kmax = k; break; }
    }
    float* a1 = abase;
    float* a2 = a1 + (size_t)kmax * 128 * HW;
    float* a3 = a1;   // layer-3 output reuses a1's (dead) space

    prep_kernel<<<(128 * 256 + 64 * 128 + 32 * 64 + 255) / 256, 256, 0, stream>>>(
        pw1w, pw2w, pw3w, wb1, wb2, wt3);

    for (int b0 = 0; b0 < 8; b0 += kmax) {
        int kc = (8 - b0 < kmax) ? (8 - b0) : kmax;
        const float* xb = x + (size_t)b0 * 256 * HW;
        int grid64 = kc * 256;

        dsconv_mfma<256, 128><<<grid64, 256, 0, stream>>>(
            xb, dw1w, dw1b, wb1, pw1b, a1);
        dsconv_mfma<128, 64><<<grid64, 256, 0, stream>>>(
            a1, dw2w, dw2b, wb2, pw2b, a2);
        dsconv_kernel<64, 32, 2><<<grid64, 256, 0, stream>>>(
            a2, dw3w, dw3b, wt3, pw3b, a3);
        final_kernel<<<grid64, 256, 0, stream>>>(
            xb, a3, dw4w, dw4b, pw4w, pw4b,
            outp + (size_t)b0 * 256 * HW, chat + (size_t)b0 * HW * 9);
    }
}

// Round 7
// 216.640 us; speedup vs baseline: 2.3620x; 2.3620x over previous
//
#include <hip/hip_runtime.h>
#include <math.h>

// Problem constants (setup_inputs): B=8, C=256, H=64, W=256
#define BH_ 64
#define BW_ 256
constexpr size_t HW = (size_t)BH_ * BW_;   // 16384

using f32x4   = __attribute__((ext_vector_type(4))) float;
using short8  = __attribute__((ext_vector_type(8))) short;
using short4v = __attribute__((ext_vector_type(4))) short;

__device__ __forceinline__ short f2bf(float f) {
    unsigned u = __float_as_uint(f);
    u += 0x7fffu + ((u >> 16) & 1u);     // RNE to bf16
    return (short)(u >> 16);
}
__device__ __forceinline__ float bf2f(short s) {
    return __uint_as_float(((unsigned)(unsigned short)s) << 16);
}

// XCD-aware block swizzle: consecutive logical ids land on the same XCD.
// gridDim.x is always kc*256 (divisible by 8) -> bijective.
__device__ __forceinline__ int xcd_swizzle() {
    const int rb  = blockIdx.x;
    const int cpx = gridDim.x >> 3;
    return (rb & 7) * cpx + (rb >> 3);
}

// ---------------------------------------------------------------------------
// Prep: pw1/pw2 -> bf16; pw3 -> fp32 transposed (CI,CO).
// ---------------------------------------------------------------------------
__global__ __launch_bounds__(256)
void prep_kernel(const float* __restrict__ p1,   // (128,256)
                 const float* __restrict__ p2,   // (64,128)
                 const float* __restrict__ p3,   // (32,64)
                 short* __restrict__ wb1,        // (128,256) bf16
                 short* __restrict__ wb2,        // (64,128) bf16
                 float* __restrict__ wt3)        // (64,32) f32
{
    int idx = blockIdx.x * 256 + threadIdx.x;
    if (idx < 128 * 256) {
        wb1[idx] = f2bf(p1[idx]);
    } else if (idx < 128 * 256 + 64 * 128) {
        int r = idx - 128 * 256;
        wb2[r] = f2bf(p2[r]);
    } else if (idx < 128 * 256 + 64 * 128 + 32 * 64) {
        int r = idx - (128 * 256 + 64 * 128);
        int ci = r / 32, co = r % 32;
        wt3[r] = p3[co * 64 + ci];
    }
}

// ---------------------------------------------------------------------------
// MFMA depthwise-separable layer (bf16 GEMM, fp32 dw): layers 1 and 2.
// Software-pipelined, double-buffered LDS, one barrier per chunk,
// __launch_bounds__(256,4) (r6 lesson: never force 8 -> spills).
// INBF: input activations bf16 (layer 2); else fp32 (layer 1, x).
// Output activations are written bf16.
// ---------------------------------------------------------------------------
template<int CI, int CO, bool INBF>
__global__ __launch_bounds__(256, 4)
void dsconv_mfma(const void* __restrict__ xin_,   // (kc, CI, H, W) f32|bf16
                 const float* __restrict__ dww,   // (CI, 9)
                 const float* __restrict__ dwb,   // (CI)
                 const short* __restrict__ wBf,   // (CO, CI) bf16
                 const float* __restrict__ pwb,   // (CO)
                 short* __restrict__ out)         // (kc, CO, H, W) bf16
{
    constexpr int CIC = 32;
    constexpr int PX  = 64;
    constexpr int NT  = CO / 16;
    constexpr int WNT = NT / 4;            // n-tiles per wave (2 L1, 1 L2)
    constexpr int ST  = 40;                // padded row stride in shorts
    constexpr int NC  = CI / CIC;          // chunks (8 L1, 4 L2)
    constexpr int SPT = (CO * CIC) / 256;  // B shorts/thread
    constexpr int TPR = CIC / SPT;
    constexpr int NB8 = SPT / 8;
    static_assert(NT % 4 == 0 && CI % CIC == 0, "geometry");

    __shared__ short Abuf[2][PX * ST];
    __shared__ short Bbuf[2][CO * ST];

    const int t    = threadIdx.x;
    const int w    = t >> 6;
    const int lane = t & 63;
    const int bid  = xcd_swizzle();
    const int jt   = bid & 3;              // W/64 = 4
    const int i    = (bid >> 2) & 63;      // H
    const int b    = bid >> 8;
    const int j0   = jt * PX;

    const int ci_l = t >> 3;               // 0..31
    const int g    = t & 7;
    const int jq   = j0 + g * 8;
    const bool vtop = (i > 0), vbot = (i < BH_ - 1);

    const int bco   = t / TPR;
    const int bsub  = t % TPR;
    const int bswz  = ((bco >> 3) & 7) << 3;
    const int bbase = bco * ST + bsub * SPT;

    const int lm = lane & 15;
    const int kb = lane >> 4;

    f32x4 acc[4][WNT];
    #pragma unroll
    for (int q = 0; q < WNT; ++q) {
        float bv = pwb[(w * WNT + q) * 16 + lm];
        #pragma unroll
        for (int mt = 0; mt < 4; ++mt) {
            f32x4 z = {bv, bv, bv, bv};
            acc[mt][q] = z;
        }
    }

    float  xw[3][10];
    float  wv9[9];
    float  dwbv;
    short8 bst[NB8];

    auto LOADX = [&](int cc) {
        const int ci = cc + ci_l;
        #pragma unroll
        for (int di = 0; di < 3; ++di) {
            const bool ok = (di == 0) ? vtop : (di == 2) ? vbot : true;
            if (ok) {
                if constexpr (INBF) {
                    const short* xp = (const short*)xin_ + ((size_t)b * CI + ci) * HW;
                    const short* xr = xp + (size_t)(i + di - 1) * BW_ + jq;
                    xw[di][0] = (jq > 0) ? bf2f(xr[-1]) : 0.f;
                    short8 S = *reinterpret_cast<const short8*>(xr);
                    #pragma unroll
                    for (int e = 0; e < 8; ++e) xw[di][1 + e] = bf2f(S[e]);
                    xw[di][9] = (jq + 8 < BW_) ? bf2f(xr[8]) : 0.f;
                } else {
                    const float* xp = (const float*)xin_ + ((size_t)b * CI + ci) * HW;
                    const float* xr = xp + (size_t)(i + di - 1) * BW_ + jq;
                    xw[di][0] = (jq > 0) ? xr[-1] : 0.f;
                    float4 A = *reinterpret_cast<const float4*>(xr);
                    float4 Bq = *reinterpret_cast<const float4*>(xr + 4);
                    xw[di][1] = A.x; xw[di][2] = A.y; xw[di][3] = A.z; xw[di][4] = A.w;
                    xw[di][5] = Bq.x; xw[di][6] = Bq.y; xw[di][7] = Bq.z; xw[di][8] = Bq.w;
                    xw[di][9] = (jq + 8 < BW_) ? xr[8] : 0.f;
                }
            } else {
                #pragma unroll
                for (int e = 0; e < 10; ++e) xw[di][e] = 0.f;
            }
        }
        const float* wkp = dww + ci * 9;
        #pragma unroll
        for (int k = 0; k < 9; ++k) wv9[k] = wkp[k];
        dwbv = dwb[ci];
    };

    auto LOADB = [&](int cc) {
        const short* src = wBf + (size_t)bco * CI + cc + bsub * SPT;
        #pragma unroll
        for (int jj = 0; jj < NB8; ++jj)
            bst[jj] = *reinterpret_cast<const short8*>(&src[jj * 8]);
    };

    auto STORE = [&](int nb) {
        #pragma unroll
        for (int jj = 0; jj < NB8; ++jj)
            *reinterpret_cast<short8*>(&Bbuf[nb][(bbase + jj * 8) ^ bswz]) = bst[jj];
        float o[8];
        #pragma unroll
        for (int e = 0; e < 8; ++e) o[e] = dwbv;
        #pragma unroll
        for (int di = 0; di < 3; ++di) {
            const float w0 = wv9[di * 3 + 0];
            const float w1 = wv9[di * 3 + 1];
            const float w2 = wv9[di * 3 + 2];
            #pragma unroll
            for (int e = 0; e < 8; ++e)
                o[e] += w0 * xw[di][e] + w1 * xw[di][e + 1] + w2 * xw[di][e + 2];
        }
        #pragma unroll
        for (int e = 0; e < 8; ++e) {
            int px = g * 8 + e;
            int sa = (px * ST + ci_l) ^ (((px >> 3) & 7) << 3);
            Abuf[nb][sa] = f2bf(o[e]);
        }
    };

    auto MFMASTEP = [&](int nb) {
        short8 bfrag[WNT];
        #pragma unroll
        for (int q = 0; q < WNT; ++q) {
            int co = (w * WNT + q) * 16 + lm;
            int sa = (co * ST + kb * 8) ^ (((co >> 3) & 7) << 3);
            bfrag[q] = *reinterpret_cast<const short8*>(&Bbuf[nb][sa]);
        }
        #pragma unroll
        for (int mt = 0; mt < 4; ++mt) {
            int px = mt * 16 + lm;
            int sa = (px * ST + kb * 8) ^ (((px >> 3) & 7) << 3);
            short8 af = *reinterpret_cast<const short8*>(&Abuf[nb][sa]);
            #pragma unroll
            for (int q = 0; q < WNT; ++q)
                acc[mt][q] = __builtin_amdgcn_mfma_f32_16x16x32_bf16(
                    af, bfrag[q], acc[mt][q], 0, 0, 0);
        }
    };

    LOADX(0); LOADB(0);
    STORE(0);
    __syncthreads();

    for (int c = 0; c < NC; ++c) {
        if (c + 1 < NC) { LOADX((c + 1) * CIC); LOADB((c + 1) * CIC); }
        MFMASTEP(c & 1);
        if (c + 1 < NC) {
            STORE((c + 1) & 1);
            __syncthreads();
        }
    }

    // ---- epilogue: ReLU + bf16 short4 stores ----
    #pragma unroll
    for (int mt = 0; mt < 4; ++mt) {
        #pragma unroll
        for (int q = 0; q < WNT; ++q) {
            int co = (w * WNT + q) * 16 + lm;
            short* op = out + (((size_t)b * CO + co) * BH_ + i) * BW_
                        + j0 + mt * 16 + kb * 4;
            short4v v;
            v[0] = f2bf(fmaxf(acc[mt][q][0], 0.f));
            v[1] = f2bf(fmaxf(acc[mt][q][1], 0.f));
            v[2] = f2bf(fmaxf(acc[mt][q][2], 0.f));
            v[3] = f2bf(fmaxf(acc[mt][q][3], 0.f));
            *reinterpret_cast<short4v*>(op) = v;
        }
    }
}

// ---------------------------------------------------------------------------
// fp32-GEMM depthwise-separable layer (layer 3): bf16 in, bf16 out.
// ---------------------------------------------------------------------------
template<int CI, int CO, int CPT>
__global__ __launch_bounds__(256, 4)
void dsconv_kernel(const short* __restrict__ xin,  // (kc, CI, H, W) bf16
                   const float* __restrict__ dww,
                   const float* __restrict__ dwb,
                   const float* __restrict__ wT,    // (CI, CO) transposed pw
                   const float* __restrict__ pwb,
                   short* __restrict__ out)         // (kc, CO, H, W) bf16
{
    constexpr int CIC = 32;
    constexpr int PX  = 64;
    static_assert(CO / CPT == 16, "co groups must be 16");

    __shared__ float dwbuf[CIC * PX];
    __shared__ float wbuf[CIC * CO];

    const int t   = threadIdx.x;
    const int bid = xcd_swizzle();
    const int jt  = bid & 3;
    const int i   = (bid >> 2) & 63;
    const int b   = bid >> 8;
    const int j0  = jt * PX;

    const int px_g = t & 15;
    const int co_g = t >> 4;
    const int co0  = co_g * CPT;
    const int p0   = px_g * 4;

    const int ci_local = t >> 3;
    const int g        = t & 7;
    const int jq       = j0 + g * 8;

    float acc[CPT][4];
    #pragma unroll
    for (int ii = 0; ii < CPT; ++ii) {
        float bv = pwb[co0 + ii];
        #pragma unroll
        for (int jj = 0; jj < 4; ++jj) acc[ii][jj] = bv;
    }

    for (int cc = 0; cc < CI; cc += CIC) {
        __syncthreads();
        {
            const float* src = wT + (size_t)cc * CO;
            #pragma unroll
            for (int idx = t * 4; idx < CIC * CO; idx += 1024)
                *reinterpret_cast<float4*>(&wbuf[idx]) =
                    *reinterpret_cast<const float4*>(&src[idx]);
        }
        {
            const int ci = cc + ci_local;
            const float* wk = dww + ci * 9;
            float w[9];
            #pragma unroll
            for (int k = 0; k < 9; ++k) w[k] = wk[k];
            float o[8];
            float bv = dwb[ci];
            #pragma unroll
            for (int e = 0; e < 8; ++e) o[e] = bv;

            const short* xp = xin + ((size_t)b * CI + ci) * HW;
            #pragma unroll
            for (int di = -1; di <= 1; ++di) {
                int ii2 = i + di;
                if ((unsigned)ii2 < (unsigned)BH_) {
                    const short* xr = xp + (size_t)ii2 * BW_ + jq;
                    float v[10];
                    v[0] = (jq > 0) ? bf2f(xr[-1]) : 0.f;
                    short8 S = *reinterpret_cast<const short8*>(xr);
                    #pragma unroll
                    for (int e = 0; e < 8; ++e) v[1 + e] = bf2f(S[e]);
                    v[9] = (jq + 8 < BW_) ? bf2f(xr[8]) : 0.f;
                    const float w0 = w[(di + 1) * 3 + 0];
                    const float w1 = w[(di + 1) * 3 + 1];
                    const float w2 = w[(di + 1) * 3 + 2];
                    #pragma unroll
                    for (int e = 0; e < 8; ++e)
                        o[e] += w0 * v[e] + w1 * v[e + 1] + w2 * v[e + 2];
                }
            }
            float4* dst = reinterpret_cast<float4*>(&dwbuf[ci_local * PX + g * 8]);
            dst[0] = make_float4(o[0], o[1], o[2], o[3]);
            dst[1] = make_float4(o[4], o[5], o[6], o[7]);
        }
        __syncthreads();

        #pragma unroll 4
        for (int k = 0; k < CIC; ++k) {
            float4 dq = *reinterpret_cast<const float4*>(&dwbuf[k * PX + p0]);
            float dv[4] = {dq.x, dq.y, dq.z, dq.w};
            float wv2[CPT];
            if constexpr (CPT == 2) {
                float2 wq = *reinterpret_cast<const float2*>(&wbuf[k * CO + co0]);
                wv2[0] = wq.x; wv2[1] = wq.y;
            } else {
                float4 wq = *reinterpret_cast<const float4*>(&wbuf[k * CO + co0]);
                #pragma unroll
                for (int ii = 0; ii < CPT && ii < 4; ++ii) wv2[ii] = (&wq.x)[ii];
            }
            #pragma unroll
            for (int ii = 0; ii < CPT; ++ii)
                #pragma unroll
                for (int jj = 0; jj < 4; ++jj)
                    acc[ii][jj] += wv2[ii] * dv[jj];
        }
    }

    #pragma unroll
    for (int ii = 0; ii < CPT; ++ii) {
        short4v v;
        v[0] = f2bf(fmaxf(acc[ii][0], 0.f));
        v[1] = f2bf(fmaxf(acc[ii][1], 0.f));
        v[2] = f2bf(fmaxf(acc[ii][2], 0.f));
        v[3] = f2bf(fmaxf(acc[ii][3], 0.f));
        short* op = out + (((size_t)b * CO + co0 + ii) * BH_ + i) * BW_ + j0 + p0;
        *reinterpret_cast<short4v*>(op) = v;
    }
}

// ---------------------------------------------------------------------------
// Final fused kernel (r5 structure + swizzle + bf16 a3):
// dw4 + pw(32->9) + softmax + char_attn + dynamic conv (8 px x 8 ch/thread).
// ---------------------------------------------------------------------------
__global__ __launch_bounds__(256, 4)
void final_kernel(const float* __restrict__ x,    // (kc,256,H,W) f32
                  const short* __restrict__ a3,   // (kc,32,H,W) bf16
                  const float* __restrict__ dww,
                  const float* __restrict__ dwb,
                  const float* __restrict__ pww,
                  const float* __restrict__ pwb,
                  float* __restrict__ out,
                  float* __restrict__ chat)
{
    constexpr int PX = 64;
    __shared__ float dwbuf[32 * PX];
    __shared__ float attL[9][PX];

    const int t   = threadIdx.x;
    const int bid = xcd_swizzle();
    const int jt  = bid & 3;
    const int i   = (bid >> 2) & 63;
    const int b   = bid >> 8;
    const int j0  = jt * PX;
    const int g   = t & 7;
    const int jq  = j0 + g * 8;

    // ---- dw4 on bf16 a3: 32 ch x 64 px ----
    {
        const int ci = t >> 3;
        const float* wk = dww + ci * 9;
        float w[9];
        #pragma unroll
        for (int k = 0; k < 9; ++k) w[k] = wk[k];
        float o[8];
        float bv = dwb[ci];
        #pragma unroll
        for (int e = 0; e < 8; ++e) o[e] = bv;

        const short* xp = a3 + ((size_t)b * 32 + ci) * HW;
        #pragma unroll
        for (int di = -1; di <= 1; ++di) {
            int ii2 = i + di;
            if ((unsigned)ii2 < (unsigned)BH_) {
                const short* xr = xp + (size_t)ii2 * BW_ + jq;
                float v[10];
                v[0] = (jq > 0) ? bf2f(xr[-1]) : 0.f;
                short8 S = *reinterpret_cast<const short8*>(xr);
                #pragma unroll
                for (int e = 0; e < 8; ++e) v[1 + e] = bf2f(S[e]);
                v[9] = (jq + 8 < BW_) ? bf2f(xr[8]) : 0.f;
                const float w0 = w[(di + 1) * 3 + 0];
                const float w1 = w[(di + 1) * 3 + 1];
                const float w2 = w[(di + 1) * 3 + 2];
                #pragma unroll
                for (int e = 0; e < 8; ++e)
                    o[e] += w0 * v[e] + w1 * v[e + 1] + w2 * v[e + 2];
            }
        }
        float4* dst = reinterpret_cast<float4*>(&dwbuf[(t >> 3) * PX + g * 8]);
        dst[0] = make_float4(o[0], o[1], o[2], o[3]);
        dst[1] = make_float4(o[4], o[5], o[6], o[7]);
    }
    __syncthreads();

    // ---- logits: 9 co x 64 px ----
    for (int idx = t; idx < 9 * PX; idx += 256) {
        int co = idx >> 6;
        int px = idx & 63;
        float acc = pwb[co];
        #pragma unroll
        for (int ci = 0; ci < 32; ++ci)
            acc += pww[co * 32 + ci] * dwbuf[ci * PX + px];
        attL[co][px] = acc;
    }
    __syncthreads();

    // ---- softmax over 9 taps ----
    if (t < PX) {
        float v[9];
        float m = -1e30f;
        #pragma unroll
        for (int k = 0; k < 9; ++k) { v[k] = attL[k][t]; m = fmaxf(m, v[k]); }
        float s = 0.f;
        #pragma unroll
        for (int k = 0; k < 9; ++k) { v[k] = __expf(v[k] - m); s += v[k]; }
        float inv = 1.f / s;
        #pragma unroll
        for (int k = 0; k < 9; ++k) attL[k][t] = v[k] * inv;
    }
    __syncthreads();

    // ---- char_attn: (b,i,j,9) contiguous ----
    {
        size_t base = (((size_t)b * BH_ + i) * BW_ + j0) * 9;
        for (int idx = t; idx < PX * 9; idx += 256)
            chat[base + idx] = attL[idx % 9][idx / 9];
    }

    // ---- att -> registers (8 px per thread) ----
    float ar[9][8];
    #pragma unroll
    for (int k = 0; k < 9; ++k) {
        float4 a0 = *reinterpret_cast<const float4*>(&attL[k][g * 8]);
        float4 a1 = *reinterpret_cast<const float4*>(&attL[k][g * 8 + 4]);
        ar[k][0] = a0.x; ar[k][1] = a0.y; ar[k][2] = a0.z; ar[k][3] = a0.w;
        ar[k][4] = a1.x; ar[k][5] = a1.y; ar[k][6] = a1.z; ar[k][7] = a1.w;
    }

    // ---- dynamic 3x3 conv: 8 px x 8 channels per thread ----
    const int c0 = t >> 3;
    for (int c = c0; c < 256; c += 32) {
        const float* xp = x + ((size_t)b * 256 + c) * HW;
        float v3[3][10];
        #pragma unroll
        for (int di = 0; di < 3; ++di) {
            int ii2 = i + di - 1;
            if ((unsigned)ii2 < (unsigned)BH_) {
                const float* xr = xp + (size_t)ii2 * BW_ + jq;
                v3[di][0] = (jq > 0) ? xr[-1] : 0.f;
                float4 A = *reinterpret_cast<const float4*>(xr);
                float4 Bq = *reinterpret_cast<const float4*>(xr + 4);
                v3[di][1] = A.x; v3[di][2] = A.y; v3[di][3] = A.z; v3[di][4] = A.w;
                v3[di][5] = Bq.x; v3[di][6] = Bq.y; v3[di][7] = Bq.z; v3[di][8] = Bq.w;
                v3[di][9] = (jq + 8 < BW_) ? xr[8] : 0.f;
            } else {
                #pragma unroll
                for (int e = 0; e < 10; ++e) v3[di][e] = 0.f;
            }
        }
        float o[8];
        #pragma unroll
        for (int e = 0; e < 8; ++e) o[e] = 0.f;
        #pragma unroll
        for (int di = 0; di < 3; ++di)
            #pragma unroll
            for (int dj = 0; dj < 3; ++dj)
                #pragma unroll
                for (int e = 0; e < 8; ++e)
                    o[e] += v3[di][e + dj] * ar[di * 3 + dj][e];
        float* op = out + ((size_t)b * 256 + c) * HW + (size_t)i * BW_ + jq;
        *reinterpret_cast<float4*>(op)     = make_float4(o[0], o[1], o[2], o[3]);
        *reinterpret_cast<float4*>(op + 4) = make_float4(o[4], o[5], o[6], o[7]);
    }
}

// ---------------------------------------------------------------------------
extern "C" void kernel_launch(void* const* d_in, const int* in_sizes, int n_in,
                              void* d_out, int out_size, void* d_ws, size_t ws_size,
                              hipStream_t stream)
{
    const float* x    = (const float*)d_in[0];
    const float* dw1w = (const float*)d_in[1];
    const float* dw1b = (const float*)d_in[2];
    const float* pw1w = (const float*)d_in[3];
    const float* pw1b = (const float*)d_in[4];
    const float* dw2w = (const float*)d_in[5];
    const float* dw2b = (const float*)d_in[6];
    const float* pw2w = (const float*)d_in[7];
    const float* pw2b = (const float*)d_in[8];
    const float* dw3w = (const float*)d_in[9];
    const float* dw3b = (const float*)d_in[10];
    const float* pw3w = (const float*)d_in[11];
    const float* pw3b = (const float*)d_in[12];
    const float* dw4w = (const float*)d_in[13];
    const float* dw4b = (const float*)d_in[14];
    const float* pw4w = (const float*)d_in[15];
    const float* pw4b = (const float*)d_in[16];

    float* outp = (float*)d_out;
    float* chat = outp + (size_t)8 * 256 * HW;

    // ws layout (bytes): wb1 65536 | wb2 16384 | wt3 8192 | a1 bf16 | a2 bf16
    short* wb1 = (short*)d_ws;
    short* wb2 = wb1 + 128 * 256;
    float* wt3 = (float*)((char*)d_ws + 81920);
    short* abase = (short*)((char*)d_ws + 90112);

    int kmax = 1;
    for (int k = 8; k >= 1; k >>= 1) {
        size_t need = 90112 + (size_t)k * (128 + 64) * HW * sizeof(short);
        if (need <= ws_size) { kmax = k; break; }
    }
    short* a1 = abase;
    short* a2 = a1 + (size_t)kmax * 128 * HW;
    short* a3 = a1;   // layer-3 output reuses a1's (dead) space

    prep_kernel<<<(128 * 256 + 64 * 128 + 32 * 64 + 255) / 256, 256, 0, stream>>>(
        pw1w, pw2w, pw3w, wb1, wb2, wt3);

    for (int b0 = 0; b0 < 8; b0 += kmax) {
        int kc = (8 - b0 < kmax) ? (8 - b0) : kmax;
        const float* xb = x + (size_t)b0 * 256 * HW;
        int grid64 = kc * 256;

        dsconv_mfma<256, 128, false><<<grid64, 256, 0, stream>>>(
            xb, dw1w, dw1b, wb1, pw1b, a1);
        dsconv_mfma<128, 64, true><<<grid64, 256, 0, stream>>>(
            a1, dw2w, dw2b, wb2, pw2b, a2);
        dsconv_kernel<64, 32, 2><<<grid64, 256, 0, stream>>>(
            a2, dw3w, dw3b, wt3, pw3b, a3);
        final_kernel<<<grid64, 256, 0, stream>>>(
            xb, a3, dw4w, dw4b, pw4w, pw4b,
            outp + (size_t)b0 * 256 * HW, chat + (size_t)b0 * HW * 9);
    }
}